// Round 2
// baseline (64297.479 us; speedup 1.0000x reference)
//
#include <hip/hip_runtime.h>
#include <cstdint>
#include <cstddef>

// Problem dims: B=32, T=2048, D=512, H=512, 4H=2048
#define TT 2048
#define DD 512

// ---------------------------------------------------------------------------
// Phase 1 (chunked): xp[m][n] = inputs[row(m)][:] . Wi[:][n] + bias[n]
// Chunk-local m = b*T_CH + tl ; global row = b*2048 + t0 + tl.
// fp32 vector GEMM, 128x128x16 tiles, 8x8 per thread.
// ---------------------------------------------------------------------------
#define BM 128
#define BN 128
#define BK 16

__global__ __launch_bounds__(256) void xproj_gemm(
    const float* __restrict__ A,    // [32*2048, 512]
    const float* __restrict__ W,    // [512, 2048]
    const float* __restrict__ bias, // [2048]
    float* __restrict__ C,          // [32*T_CH, 2048] chunk-local
    int t0, int tmask, int tlog)    // T_CH = tmask+1 = 1<<tlog
{
    __shared__ float As[BK][BM + 4];   // [k][m], transposed on load
    __shared__ float Bs[BK][BN + 4];   // [k][n]
    const int tid = threadIdx.x;
    const int nt = blockIdx.x;
    const int mt = blockIdx.y;
    const int m_base = mt * BM;        // chunk-local row base
    const int n_base = nt * BN;
    const int ty = tid >> 4;
    const int tx = tid & 15;

    float acc[8][8];
#pragma unroll
    for (int i = 0; i < 8; ++i)
#pragma unroll
        for (int j = 0; j < 8; ++j) acc[i][j] = 0.f;

    for (int k0 = 0; k0 < DD; k0 += BK) {
#pragma unroll
        for (int j = 0; j < 2; ++j) {
            int idx = tid * 2 + j;             // 0..511
            int rowl = idx >> 2, q = idx & 3;  // A: 128 rows x 4 float4
            int rc = m_base + rowl;            // chunk-local row
            int rg = ((rc >> tlog) << 11) + t0 + (rc & tmask);  // global row
            float4 av = *(const float4*)(A + (size_t)rg * DD + k0 + q * 4);
            As[q * 4 + 0][rowl] = av.x;
            As[q * 4 + 1][rowl] = av.y;
            As[q * 4 + 2][rowl] = av.z;
            As[q * 4 + 3][rowl] = av.w;
            int kr = idx >> 5, nq = idx & 31;  // B: 16 rows x 32 float4
            *(float4*)&Bs[kr][nq * 4] =
                *(const float4*)(W + (size_t)(k0 + kr) * 2048 + n_base + nq * 4);
        }
        __syncthreads();
#pragma unroll
        for (int kk = 0; kk < BK; ++kk) {
            float a[8], bb[8];
            *(float4*)&a[0]  = *(const float4*)&As[kk][ty * 8];
            *(float4*)&a[4]  = *(const float4*)&As[kk][ty * 8 + 4];
            *(float4*)&bb[0] = *(const float4*)&Bs[kk][tx * 8];
            *(float4*)&bb[4] = *(const float4*)&Bs[kk][tx * 8 + 4];
#pragma unroll
            for (int i = 0; i < 8; ++i)
#pragma unroll
                for (int j = 0; j < 8; ++j)
                    acc[i][j] = fmaf(a[i], bb[j], acc[i][j]);
        }
        __syncthreads();
    }
#pragma unroll
    for (int i = 0; i < 8; ++i) {
        size_t m = (size_t)(m_base + ty * 8 + i);    // chunk-local store row
#pragma unroll
        for (int j = 0; j < 8; j += 4) {
            int n = n_base + tx * 8 + j;
            float4 v;
            v.x = acc[i][j + 0] + bias[n + 0];
            v.y = acc[i][j + 1] + bias[n + 1];
            v.z = acc[i][j + 2] + bias[n + 2];
            v.w = acc[i][j + 3] + bias[n + 3];
            *(float4*)(C + m * 2048 + n) = v;
        }
    }
}

// ---------------------------------------------------------------------------
// Phase 2: persistent LSTM scan over one T-chunk.
// 4 groups x 128 blocks. Group g owns batches [8g, 8g+8).
// Block gb (0..127) owns h-cols [4gb, 4gb+4) -> 16 Wh cols LDS-resident.
// h exchanged via global ping-pong + per-group sense-reversing barrier.
// c-state persists across chunk launches in cbuf.
// ---------------------------------------------------------------------------
#define NGRP 4
#define BPG  128
#define WHP  516   // padded row stride (floats): conflict-free b128 reads
#define HP   516

__device__ __forceinline__ void group_barrier(unsigned* cnt, unsigned* gen, unsigned nb) {
    __syncthreads();   // drains vmcnt: this block's stores complete before arrive
    if (threadIdx.x == 0) {
        unsigned g = __hip_atomic_load(gen, __ATOMIC_RELAXED, __HIP_MEMORY_SCOPE_AGENT);
        unsigned old = __hip_atomic_fetch_add(cnt, 1u, __ATOMIC_ACQ_REL, __HIP_MEMORY_SCOPE_AGENT);
        if (old == nb - 1u) {
            __hip_atomic_store(cnt, 0u, __ATOMIC_RELAXED, __HIP_MEMORY_SCOPE_AGENT);
            __hip_atomic_store(gen, g + 1u, __ATOMIC_RELEASE, __HIP_MEMORY_SCOPE_AGENT);
        } else {
            while (__hip_atomic_load(gen, __ATOMIC_ACQUIRE, __HIP_MEMORY_SCOPE_AGENT) == g) {
                __builtin_amdgcn_s_sleep(4);
            }
        }
    }
    __syncthreads();
}

__global__ __launch_bounds__(256) void lstm_scan(
    const float* __restrict__ xp,   // [32, T_CH, 2048] chunk of x@Wi + b
    const float* __restrict__ Wh,   // [512, 2048]
    const float* __restrict__ c0,   // [32, 512]
    const float* __restrict__ h0,   // [32, 512]
    float* __restrict__ out,        // [32, 2048, 512]
    float* __restrict__ hbuf,       // [2][32][512] ping-pong (persists)
    float* __restrict__ cbuf,       // [32][512] c-state (persists)
    unsigned* __restrict__ bar,     // per-group {cnt, gen}
    int t0, int T_CH)
{
    __shared__ float wh_lds[16 * WHP];  // 16 cols x 512 (padded)   33,024 B
    __shared__ float h_lds[8 * HP];     // 8 batches x 512 (padded) 16,512 B
    __shared__ float zpart[256];
    __shared__ float xs[8 * 16];

    const int tid = threadIdx.x;
    const int blk = blockIdx.x;
    const int g   = blk >> 7;     // group 0..3
    const int gb  = blk & 127;
    const int j0  = gb * 4;       // owned h-col base

    unsigned* cnt = bar + g * 64;
    unsigned* gen = bar + g * 64 + 16;

    // ---- stage Wh slice into LDS (once per launch) ----
#pragma unroll
    for (int it = 0; it < 8; ++it) {
        int idx = tid + it * 256;          // (k, gate)
        int gate = idx & 3, k = idx >> 2;
        float4 v = *(const float4*)(Wh + (size_t)k * 2048 + gate * 512 + j0);
        wh_lds[(gate * 4 + 0) * WHP + k] = v.x;
        wh_lds[(gate * 4 + 1) * WHP + k] = v.y;
        wh_lds[(gate * 4 + 2) * WHP + k] = v.z;
        wh_lds[(gate * 4 + 3) * WHP + k] = v.w;
    }

    // compute-role: cc = col (gate*4+jl), cb = batch, ks = k-half
    const int cc = tid >> 4;
    const int rr = tid & 15;
    const int cb = rr >> 1;
    const int ks = rr & 1;

    // gate-role (tid < 32): b = tid>>2, j = tid&3
    float creg = 0.f;
    if (tid < 32) {
        int b = tid >> 2, j = tid & 3;
        size_t o = (size_t)(8 * g + b) * 512 + j0 + j;
        if (t0 == 0) {
            creg = c0[o];
            hbuf[o] = h0[o];   // parity-0 buffer init
        } else {
            creg = cbuf[o];    // h already in hbuf[(t0&1)] from prev chunk
        }
    }
    group_barrier(cnt, gen, BPG);

    const float4* w4 = (const float4*)(wh_lds + cc * WHP + ks * 256);
    const float4* h4 = (const float4*)(h_lds + cb * HP + ks * 256);

    for (int tl = 0; tl < T_CH; ++tl) {
        const int t = t0 + tl;
        const int cur = t & 1;

        // issue xp load early
        float4 xv4;
        if (tid < 32) {
            int b = tid >> 2, gate = tid & 3;
            xv4 = *(const float4*)(xp + ((size_t)(8 * g + b) * T_CH + tl) * 2048 + gate * 512 + j0);
        }

        // stage group h (8 x 512) into LDS, coalesced float4
        {
            const float* hsrc = hbuf + (size_t)cur * (32 * 512) + (size_t)(8 * g) * 512;
            int w = tid * 16;
#pragma unroll
            for (int i = 0; i < 4; ++i) {
                float4 v = *(const float4*)(hsrc + w + i * 4);
                int b = (w + i * 4) >> 9, k = (w + i * 4) & 511;
                *(float4*)(h_lds + b * HP + k) = v;
            }
        }
        __syncthreads();

        // partial dot for (col cc, batch cb, k-half ks)
        float4 a4 = make_float4(0.f, 0.f, 0.f, 0.f);
#pragma unroll 8
        for (int kk = 0; kk < 64; ++kk) {
            float4 hv = h4[kk], wv = w4[kk];
            a4.x = fmaf(hv.x, wv.x, a4.x);
            a4.y = fmaf(hv.y, wv.y, a4.y);
            a4.z = fmaf(hv.z, wv.z, a4.z);
            a4.w = fmaf(hv.w, wv.w, a4.w);
        }
        zpart[tid] = (a4.x + a4.y) + (a4.z + a4.w);
        if (tid < 32) {
            int b = tid >> 2, gate = tid & 3;
            *(float4*)(xs + (b * 4 + gate) * 4) = xv4;
        }
        __syncthreads();

        // gates: flax order i, f, g, o
        if (tid < 32) {
            int b = tid >> 2, j = tid & 3;
            float z[4];
#pragma unroll
            for (int gate = 0; gate < 4; ++gate) {
                int ccg = gate * 4 + j;
                z[gate] = xs[(b * 4 + gate) * 4 + j]
                        + zpart[ccg * 16 + b * 2 + 0]
                        + zpart[ccg * 16 + b * 2 + 1];
            }
            float si = 1.f / (1.f + expf(-z[0]));
            float sf = 1.f / (1.f + expf(-z[1]));
            float tg = tanhf(z[2]);
            float so = 1.f / (1.f + expf(-z[3]));
            float cn = sf * creg + si * tg;
            float hn = so * tanhf(cn);
            creg = cn;
            hbuf[(size_t)(cur ^ 1) * (32 * 512) + (size_t)(8 * g + b) * 512 + j0 + j] = hn;
            out[((size_t)(8 * g + b) * TT + t) * 512 + j0 + j] = hn;
        }
        group_barrier(cnt, gen, BPG);
    }

    // persist c for next chunk
    if (tid < 32) {
        int b = tid >> 2, j = tid & 3;
        cbuf[(size_t)(8 * g + b) * 512 + j0 + j] = creg;
    }
}

// ---------------------------------------------------------------------------
extern "C" void kernel_launch(void* const* d_in, const int* in_sizes, int n_in,
                              void* d_out, int out_size, void* d_ws, size_t ws_size,
                              hipStream_t stream) {
    const float* inputs = (const float*)d_in[0];
    // d_in[1] = input_paddings: unused (reference discards it)
    const float* c0   = (const float*)d_in[2];
    const float* h0   = (const float*)d_in[3];
    const float* Wi   = (const float*)d_in[4];
    const float* Wh   = (const float*)d_in[5];
    const float* bias = (const float*)d_in[6];
    float* out = (float*)d_out;

    // ws layout: [hbuf 32768 f][cbuf 16384 f][bar 256 u32][pad][xp chunk]
    float* ws_f = (float*)d_ws;
    float* hbuf = ws_f;
    float* cbuf = ws_f + 32768;
    unsigned* bar = (unsigned*)(ws_f + 49152);
    float* xp = ws_f + 49664;                 // 16B-aligned
    const size_t extras_bytes = 49664 * sizeof(float);

    // pick largest T-chunk (pow2, <=256) whose xp slab fits in ws
    int T_CH = 256;
    while (T_CH > 32 &&
           extras_bytes + (size_t)32 * T_CH * 2048 * sizeof(float) > ws_size)
        T_CH >>= 1;
    int tlog = 31 - __builtin_clz((unsigned)T_CH);

    hipMemsetAsync(bar, 0, 256 * sizeof(unsigned), stream);

    for (int t0 = 0; t0 < TT; t0 += T_CH) {
        dim3 g1(2048 / BN, (32 * T_CH) / BM);
        xproj_gemm<<<g1, 256, 0, stream>>>(inputs, Wi, bias, xp, t0, T_CH - 1, tlog);

        const float* xp_c = xp;
        int t0_arg = t0, tch_arg = T_CH;
        void* args[] = { (void*)&xp_c, (void*)&Wh, (void*)&c0, (void*)&h0,
                         (void*)&out, (void*)&hbuf, (void*)&cbuf, (void*)&bar,
                         (void*)&t0_arg, (void*)&tch_arg };
        hipLaunchCooperativeKernel((const void*)lstm_scan, dim3(NGRP * BPG), dim3(256),
                                   args, 0, stream);
    }
}

// Round 3
// 19984.563 us; speedup vs baseline: 3.2174x; 3.2174x over previous
//
#include <hip/hip_runtime.h>
#include <cstdint>
#include <cstddef>

// Problem dims: B=32, T=2048, D=512, H=512, 4H=2048
#define TT 2048
#define DD 512

// ---------------------------------------------------------------------------
// Phase 1 (chunked): xp = inputs @ Wi + b, written in SCAN-NATIVE layout:
//   xp[tl][gate 4][g 4][gb 128][b 8][jl 4]   (T_CH*65536 floats per chunk)
// so the scan reads 512B of fully-dense 64B lines per block per step.
// fp32 vector GEMM, 128x128x16 tiles, 8x8 per thread.
// ---------------------------------------------------------------------------
#define BM 128
#define BN 128
#define BK 16

__global__ __launch_bounds__(256) void xproj_gemm(
    const float* __restrict__ A,    // [32*2048, 512]
    const float* __restrict__ W,    // [512, 2048]
    const float* __restrict__ bias, // [2048]
    float* __restrict__ C,          // xp chunk, scan layout
    int t0, int tmask, int tlog)    // T_CH = tmask+1 = 1<<tlog
{
    __shared__ float As[BK][BM + 4];   // [k][m], transposed on load
    __shared__ float Bs[BK][BN + 4];   // [k][n]
    const int tid = threadIdx.x;
    const int nt = blockIdx.x;
    const int mt = blockIdx.y;
    const int m_base = mt * BM;        // chunk-local row base (m = bglob*T_CH + tl)
    const int n_base = nt * BN;
    const int ty = tid >> 4;
    const int tx = tid & 15;

    float acc[8][8];
#pragma unroll
    for (int i = 0; i < 8; ++i)
#pragma unroll
        for (int j = 0; j < 8; ++j) acc[i][j] = 0.f;

    for (int k0 = 0; k0 < DD; k0 += BK) {
#pragma unroll
        for (int j = 0; j < 2; ++j) {
            int idx = tid * 2 + j;             // 0..511
            int rowl = idx >> 2, q = idx & 3;  // A: 128 rows x 4 float4
            int rc = m_base + rowl;            // chunk-local row
            int rg = ((rc >> tlog) << 11) + t0 + (rc & tmask);  // global input row
            float4 av = *(const float4*)(A + (size_t)rg * DD + k0 + q * 4);
            As[q * 4 + 0][rowl] = av.x;
            As[q * 4 + 1][rowl] = av.y;
            As[q * 4 + 2][rowl] = av.z;
            As[q * 4 + 3][rowl] = av.w;
            int kr = idx >> 5, nq = idx & 31;  // B: 16 rows x 32 float4
            *(float4*)&Bs[kr][nq * 4] =
                *(const float4*)(W + (size_t)(k0 + kr) * 2048 + n_base + nq * 4);
        }
        __syncthreads();
#pragma unroll
        for (int kk = 0; kk < BK; ++kk) {
            float a[8], bb[8];
            *(float4*)&a[0]  = *(const float4*)&As[kk][ty * 8];
            *(float4*)&a[4]  = *(const float4*)&As[kk][ty * 8 + 4];
            *(float4*)&bb[0] = *(const float4*)&Bs[kk][tx * 8];
            *(float4*)&bb[4] = *(const float4*)&Bs[kk][tx * 8 + 4];
#pragma unroll
            for (int i = 0; i < 8; ++i)
#pragma unroll
                for (int j = 0; j < 8; ++j)
                    acc[i][j] = fmaf(a[i], bb[j], acc[i][j]);
        }
        __syncthreads();
    }
#pragma unroll
    for (int i = 0; i < 8; ++i) {
        int m = m_base + ty * 8 + i;
        int bglob = m >> tlog, tl = m & tmask;
        int g = bglob >> 3, b = bglob & 7;
#pragma unroll
        for (int j = 0; j < 8; j += 4) {
            int n = n_base + tx * 8 + j;       // n % 4 == 0 -> jl = 0
            int gate = n >> 9, gb = (n & 511) >> 2;
            float4 v;
            v.x = acc[i][j + 0] + bias[n + 0];
            v.y = acc[i][j + 1] + bias[n + 1];
            v.z = acc[i][j + 2] + bias[n + 2];
            v.w = acc[i][j + 3] + bias[n + 3];
            size_t addr = (((((size_t)tl * 4 + gate) * 4 + g) * 128 + gb) * 8 + b) * 4;
            *(float4*)(C + addr) = v;
        }
    }
}

// ---------------------------------------------------------------------------
// Phase 2: persistent LSTM scan over one T-chunk.
// 4 groups x 128 blocks. Group g owns batches [8g, 8g+8).
// Block gb owns h-cols [4gb, 4gb+4) -> 16 Wh cols LDS-resident.
// h exchanged via agent-scope RELAXED atomics (coherence-point direct: no
// stale caches, no fences, no invalidates). Barrier = per-block flag store +
// master (gb==0) parallel poll + gen broadcast. Zero RMW, zero acq/rel.
// ---------------------------------------------------------------------------
#define NGRP 4
#define BPG  128
#define WHP  516   // padded row stride (floats): conflict-free b128 reads
#define HP   516
#define FS   32    // flag padding stride in u32 (128 B)

__device__ __forceinline__ void flag_barrier(unsigned* gflags, unsigned* ggen,
                                             int tid, int gb, unsigned e) {
    // __syncthreads lowers to s_waitcnt vmcnt(0) lgkmcnt(0); s_barrier
    // [measured m97] -> every thread's (sc1) stores are complete at the
    // coherence point before any thread arrives.
    __syncthreads();
    if (gb == 0) {
        if (tid == 0)
            __hip_atomic_store(gflags, e, __ATOMIC_RELAXED, __HIP_MEMORY_SCOPE_AGENT);
        if (tid < BPG) {
            unsigned* f = gflags + tid * FS;
            while (__hip_atomic_load(f, __ATOMIC_RELAXED, __HIP_MEMORY_SCOPE_AGENT) < e)
                __builtin_amdgcn_s_sleep(1);
        }
        __syncthreads();
        if (tid == 0)
            __hip_atomic_store(ggen, e, __ATOMIC_RELAXED, __HIP_MEMORY_SCOPE_AGENT);
    } else {
        if (tid == 0) {
            __hip_atomic_store(gflags + gb * FS, e, __ATOMIC_RELAXED, __HIP_MEMORY_SCOPE_AGENT);
            while (__hip_atomic_load(ggen, __ATOMIC_RELAXED, __HIP_MEMORY_SCOPE_AGENT) < e)
                __builtin_amdgcn_s_sleep(1);
        }
        __syncthreads();
    }
}

__global__ __launch_bounds__(256) void lstm_scan(
    const float* __restrict__ xp,   // chunk, scan layout (see xproj_gemm)
    const float* __restrict__ Wh,   // [512, 2048]
    const float* __restrict__ c0,   // [32, 512]
    const float* __restrict__ h0,   // [32, 512]
    float* __restrict__ out,        // [32, 2048, 512]
    float* hbuf,                    // [2][32][512] ping-pong (persists)
    float* __restrict__ cbuf,       // [32][512] c-state (persists)
    unsigned* __restrict__ flags,   // [4][128][FS]
    unsigned* __restrict__ gen,     // [4][FS]
    int t0, int T_CH, unsigned ep0)
{
    __shared__ float wh_lds[16 * WHP];  // 16 cols x 512 (padded)   33,024 B
    __shared__ float h_lds[8 * HP];     // 8 batches x 512 (padded) 16,512 B
    __shared__ float zpart[256];
    __shared__ float xs[8 * 16];

    const int tid = threadIdx.x;
    const int blk = blockIdx.x;
    const int g   = blk >> 7;     // group 0..3
    const int gb  = blk & 127;
    const int j0  = gb * 4;       // owned h-col base

    unsigned* gflags = flags + (size_t)g * BPG * FS;
    unsigned* ggen   = gen + g * FS;

    // ---- stage Wh slice into LDS (once per launch) ----
#pragma unroll
    for (int it = 0; it < 8; ++it) {
        int idx = tid + it * 256;          // (k, gate)
        int gate = idx & 3, k = idx >> 2;
        float4 v = *(const float4*)(Wh + (size_t)k * 2048 + gate * 512 + j0);
        wh_lds[(gate * 4 + 0) * WHP + k] = v.x;
        wh_lds[(gate * 4 + 1) * WHP + k] = v.y;
        wh_lds[(gate * 4 + 2) * WHP + k] = v.z;
        wh_lds[(gate * 4 + 3) * WHP + k] = v.w;
    }

    // compute-role: cc = col (gate*4+jl), cb = batch, ks = k-half
    const int cc = tid >> 4;
    const int rr = tid & 15;
    const int cb = rr >> 1;
    const int ks = rr & 1;

    // gate-role (tid < 32): b = tid>>2, j = tid&3
    float creg = 0.f;
    if (tid < 32) {
        int b = tid >> 2, j = tid & 3;
        size_t o = (size_t)(8 * g + b) * 512 + j0 + j;
        if (t0 == 0) {
            creg = c0[o];
            __hip_atomic_store(hbuf + o, h0[o], __ATOMIC_RELAXED, __HIP_MEMORY_SCOPE_AGENT);
        } else {
            creg = cbuf[o];    // h already in hbuf[(t0&1)] from prev chunk (sc1)
        }
    }
    unsigned ep = ep0;
    flag_barrier(gflags, ggen, tid, gb, ++ep);

    const float4* w4 = (const float4*)(wh_lds + cc * WHP + ks * 256);
    const float4* h4 = (const float4*)(h_lds + cb * HP + ks * 256);

    for (int tl = 0; tl < T_CH; ++tl) {
        const int t = t0 + tl;
        const int cur = t & 1;

        // issue xp load early (dense 512B/block/step, plain cached loads)
        float4 xv4;
        if (tid < 32) {
            int gate = tid >> 3, b = tid & 7;
            xv4 = *(const float4*)(xp +
                  ((((size_t)tl * 4 + gate) * 4 + g) * 128 + gb) * 32 + b * 4);
        }

        // stage group h (8 x 512) into LDS via coherence-point loads
        {
            const float* hsrc = hbuf + (size_t)cur * (32 * 512) + (size_t)(8 * g) * 512;
#pragma unroll
            for (int i = 0; i < 16; ++i) {
                int p = tid + i * 256;
                float v = __hip_atomic_load(hsrc + p, __ATOMIC_RELAXED, __HIP_MEMORY_SCOPE_AGENT);
                h_lds[(p >> 9) * HP + (p & 511)] = v;
            }
        }
        __syncthreads();

        // partial dot for (col cc, batch cb, k-half ks)
        float4 a4 = make_float4(0.f, 0.f, 0.f, 0.f);
#pragma unroll 8
        for (int kk = 0; kk < 64; ++kk) {
            float4 hv = h4[kk], wv = w4[kk];
            a4.x = fmaf(hv.x, wv.x, a4.x);
            a4.y = fmaf(hv.y, wv.y, a4.y);
            a4.z = fmaf(hv.z, wv.z, a4.z);
            a4.w = fmaf(hv.w, wv.w, a4.w);
        }
        zpart[tid] = (a4.x + a4.y) + (a4.z + a4.w);
        if (tid < 32) {
            int gate = tid >> 3, b = tid & 7;
            *(float4*)&xs[(b * 4 + gate) * 4] = xv4;
        }
        __syncthreads();

        // gates: flax order i, f, g, o
        if (tid < 32) {
            int b = tid >> 2, j = tid & 3;
            float z[4];
#pragma unroll
            for (int gate = 0; gate < 4; ++gate) {
                int ccg = gate * 4 + j;
                z[gate] = xs[(b * 4 + gate) * 4 + j]
                        + zpart[ccg * 16 + b * 2 + 0]
                        + zpart[ccg * 16 + b * 2 + 1];
            }
            float si = 1.f / (1.f + expf(-z[0]));
            float sf = 1.f / (1.f + expf(-z[1]));
            float tg = tanhf(z[2]);
            float so = 1.f / (1.f + expf(-z[3]));
            float cn = sf * creg + si * tg;
            float hn = so * tanhf(cn);
            creg = cn;
            __hip_atomic_store(
                hbuf + (size_t)(cur ^ 1) * (32 * 512) + (size_t)(8 * g + b) * 512 + j0 + j,
                hn, __ATOMIC_RELAXED, __HIP_MEMORY_SCOPE_AGENT);
            out[((size_t)(8 * g + b) * TT + t) * 512 + j0 + j] = hn;
        }
        flag_barrier(gflags, ggen, tid, gb, ++ep);
    }

    // persist c for next chunk launch (plain; kernel-boundary coherence)
    if (tid < 32) {
        int b = tid >> 2, j = tid & 3;
        cbuf[(size_t)(8 * g + b) * 512 + j0 + j] = creg;
    }
}

// ---------------------------------------------------------------------------
extern "C" void kernel_launch(void* const* d_in, const int* in_sizes, int n_in,
                              void* d_out, int out_size, void* d_ws, size_t ws_size,
                              hipStream_t stream) {
    const float* inputs = (const float*)d_in[0];
    // d_in[1] = input_paddings: unused (reference discards it)
    const float* c0   = (const float*)d_in[2];
    const float* h0   = (const float*)d_in[3];
    const float* Wi   = (const float*)d_in[4];
    const float* Wh   = (const float*)d_in[5];
    const float* bias = (const float*)d_in[6];
    float* out = (float*)d_out;

    // ws layout (floats): [hbuf 32768][cbuf 16384][flags 16384 u32][gen 128 u32][xp]
    float* ws_f = (float*)d_ws;
    float* hbuf = ws_f;
    float* cbuf = ws_f + 32768;
    unsigned* flags = (unsigned*)(ws_f + 49152);
    unsigned* gen   = flags + NGRP * BPG * FS;       // 16384 u32
    float* xp = ws_f + 49152 + 16384 + 128;          // 65664 (16B aligned)
    const size_t extras_bytes = 65664 * sizeof(float);

    // pick largest T-chunk (pow2, <=256) whose xp slab fits in ws
    int T_CH = 256;
    while (T_CH > 32 &&
           extras_bytes + (size_t)T_CH * 65536 * sizeof(float) > ws_size)
        T_CH >>= 1;
    int tlog = 31 - __builtin_clz((unsigned)T_CH);

    // flags/gen are 0xAA-poisoned before every call; epochs are monotone from 1
    hipMemsetAsync(flags, 0, (NGRP * BPG * FS + NGRP * FS) * sizeof(unsigned), stream);

    for (int t0 = 0; t0 < TT; t0 += T_CH) {
        dim3 g1(2048 / BN, (32 * T_CH) / BM);
        xproj_gemm<<<g1, 256, 0, stream>>>(inputs, Wi, bias, xp, t0, T_CH - 1, tlog);

        const float* xp_c = xp;
        int t0_arg = t0, tch_arg = T_CH;
        unsigned ep0 = (unsigned)(t0 / T_CH) * (unsigned)(T_CH + 1);
        void* args[] = { (void*)&xp_c, (void*)&Wh, (void*)&c0, (void*)&h0,
                         (void*)&out, (void*)&hbuf, (void*)&cbuf,
                         (void*)&flags, (void*)&gen,
                         (void*)&t0_arg, (void*)&tch_arg, (void*)&ep0 };
        hipLaunchCooperativeKernel((const void*)lstm_scan, dim3(NGRP * BPG), dim3(256),
                                   args, 0, stream);
    }
}